// Round 7
// baseline (245.986 us; speedup 1.0000x reference)
//
#include <hip/hip_runtime.h>
#include <hip/hip_bf16.h>
#include <cstdint>

typedef __attribute__((ext_vector_type(8))) __bf16 bf16v8;
typedef __attribute__((ext_vector_type(4))) float f32x4;
typedef __attribute__((ext_vector_type(4))) unsigned short ushort4v;
typedef __attribute__((ext_vector_type(8))) unsigned short ushort8v;

#define BB 8
#define NN 2048
#define DD 768

__device__ __forceinline__ float b2f(unsigned short u) {
  union { unsigned int i; float f; } c; c.i = ((unsigned int)u) << 16; return c.f;
}
__device__ __forceinline__ unsigned short f2b(float f) {
  union { float f; unsigned int i; } c; c.f = f;
  unsigned int u = c.i;
  return (unsigned short)((u + 0x7fffu + ((u >> 16) & 1u)) >> 16);
}

// ---------------- LayerNorm: f32 [16384][768] -> bf16 ----------------
__global__ __launch_bounds__(256) void ln_kernel(const float* __restrict__ x,
                                                 const float* __restrict__ gamma,
                                                 const float* __restrict__ beta,
                                                 unsigned short* __restrict__ xb) {
  int row = blockIdx.x;
  const float* xr = x + (size_t)row * DD;
  int t = threadIdx.x;
  float a0 = xr[t], a1 = xr[t + 256], a2 = xr[t + 512];
  float s = a0 + a1 + a2;
  float q = a0 * a0 + a1 * a1 + a2 * a2;
  for (int o = 32; o > 0; o >>= 1) { s += __shfl_xor(s, o); q += __shfl_xor(q, o); }
  __shared__ float red[2][4];
  int w = t >> 6, lane = t & 63;
  if (lane == 0) { red[0][w] = s; red[1][w] = q; }
  __syncthreads();
  s = red[0][0] + red[0][1] + red[0][2] + red[0][3];
  q = red[1][0] + red[1][1] + red[1][2] + red[1][3];
  float mean = s * (1.0f / DD);
  float var = q * (1.0f / DD) - mean * mean;
  float inv = rsqrtf(var + 1e-5f);
  unsigned short* o0 = xb + (size_t)row * DD;
  o0[t]       = f2b((a0 - mean) * inv * gamma[t]       + beta[t]);
  o0[t + 256] = f2b((a1 - mean) * inv * gamma[t + 256] + beta[t + 256]);
  o0[t + 512] = f2b((a2 - mean) * inv * gamma[t + 512] + beta[t + 512]);
}

// ------------- Weight concat/convert: Wcat[2304][768] bf16, scale folded into Wq -------------
__global__ __launch_bounds__(256) void wconvert(const float* __restrict__ Wq,
                                                const float* __restrict__ Wk,
                                                const float* __restrict__ Wv,
                                                unsigned short* __restrict__ Wcat) {
  int i = blockIdx.x * 256 + threadIdx.x;
  const int dd = DD * DD;
  if (i >= 3 * dd) return;
  float v;
  if (i < dd)           v = Wq[i] * 0.03608439182435161f;   // 1/sqrt(768)
  else if (i < 2 * dd)  v = Wk[i - dd];
  else                  v = Wv[i - 2 * dd];
  Wcat[i] = f2b(v);
}

// ---------------- async global->LDS (16B per lane, wave-uniform LDS base) ----------------
__device__ __forceinline__ void gload_lds16(const void* g, void* l) {
  __builtin_amdgcn_global_load_lds(
      (const __attribute__((address_space(1))) void*)g,
      (__attribute__((address_space(3))) void*)(unsigned)(uintptr_t)l,
      16, 0, 0);
}

#define BARF asm volatile("s_barrier" ::: "memory")
#define VMC0 asm volatile("s_waitcnt vmcnt(0)" ::: "memory")
#define P1   __builtin_amdgcn_s_setprio(1)
#define P0   __builtin_amdgcn_s_setprio(0)

// ---------------- 256x128 bf16 GEMM, BK=32, 2 blocks/CU, C = A * B^T ----------------
// 512 threads = 8 waves (2M x 4N); per-wave output 128x32 (8x2 frags, 64 AGPR).
// 48 KiB static LDS double-buffered; T3-minimum schedule: stage(t+1) -> other buf,
// read+MFMA(t), vmcnt(0), single barrier per K-tile. Overlap comes from the second
// resident block per CU (independent barrier domain), not in-block pipelining.
// MODE 0: QKV projection epilogue (Q / K / V-transposed)   MODE 1: bf16 store   MODE 2: f32 store
template <int MODE>
__global__ __launch_bounds__(512, 4) void gemm128(
    const unsigned short* __restrict__ A, const unsigned short* __restrict__ Bm,
    unsigned short* __restrict__ Cq, unsigned short* __restrict__ Ck,
    unsigned short* __restrict__ Cv, float* __restrict__ Cf,
    int K, int lda, int ldb,
    long aStride, long bStride, long cStride) {
  __shared__ alignas(16) unsigned short As[2][256 * 32];   // 32 KiB
  __shared__ alignas(16) unsigned short Bs[2][128 * 32];   // 16 KiB

  const int t = threadIdx.x;
  int bx = blockIdx.x, by = blockIdx.y, bz = blockIdx.z;
  {  // bijective XCD swizzle (all grids are %8==0)
    const int gx = gridDim.x, gy = gridDim.y;
    const int nwg = gx * gy * (int)gridDim.z;
    int id = bx + gx * (by + gy * bz);
    int sw = (id & 7) * (nwg >> 3) + (id >> 3);
    bx = sw % gx; int r2 = sw / gx;
    by = r2 % gy; bz = r2 / gy;
  }
  const int n0 = bx * 128, m0 = by * 256;
  const unsigned short* Ab = A + (size_t)bz * aStride;
  const unsigned short* Bb = Bm + (size_t)bz * bStride;

  const int lane = t & 63;
  const int w = t >> 6;
  const int wm = w >> 2, wn = w & 3;            // 2 x 4 wave grid
  const int frow = lane & 15;
  const int kg8 = (lane >> 4) * 8;
  const int abase = (wm * 128 + frow) * 32 + kg8;   // + mf*512
  const int bbase = (wn * 32 + frow) * 32 + kg8;    // + nf*512

  // staging: thread t -> row t>>2 (0..127), col-group t&3 (x8 elems); dest is
  // wave-uniform base + lane*16B (verified: (lane>>2)*32+(lane&3)*8 == lane*8 elems)
  const int srow = t >> 2;
  const int scol8 = (t & 3) * 8;
  const int asd = srow * 32 + scol8;
  const unsigned short* Asrc = Ab + (size_t)(m0 + srow) * lda + scol8;
  const unsigned short* Bsrc = Bb + (size_t)(n0 + srow) * ldb + scol8;

  auto stg = [&](int kt, int buf) {
    const unsigned short* sa = Asrc + kt * 32;
    gload_lds16(sa, &As[buf][asd]);
    gload_lds16(sa + (size_t)128 * lda, &As[buf][asd + 4096]);
    gload_lds16(Bsrc + kt * 32, &Bs[buf][asd]);
  };

  f32x4 acc[8][2] = {};
  const int NT = K >> 5;

  stg(0, 0);
  VMC0; BARF;

  for (int ktp = 0; ktp < NT; ktp += 2) {
#pragma unroll
    for (int sub = 0; sub < 2; ++sub) {
      const int kt = ktp + sub;
      const unsigned short* Al = As[sub];
      const unsigned short* Bl = Bs[sub];
      if (kt + 1 < NT) stg(kt + 1, sub ^ 1);
      bf16v8 bq0 = *(const bf16v8*)&Bl[bbase];
      bf16v8 bq1 = *(const bf16v8*)&Bl[bbase + 512];
      bf16v8 aq[4];
#pragma unroll
      for (int i = 0; i < 4; ++i) aq[i] = *(const bf16v8*)&Al[abase + i * 512];
      P1;
#pragma unroll
      for (int i = 0; i < 4; ++i) {
        acc[i][0] = __builtin_amdgcn_mfma_f32_16x16x32_bf16(aq[i], bq0, acc[i][0], 0, 0, 0);
        acc[i][1] = __builtin_amdgcn_mfma_f32_16x16x32_bf16(aq[i], bq1, acc[i][1], 0, 0, 0);
      }
      P0;
      __builtin_amdgcn_sched_barrier(0);   // cap operand liveness: 2nd half reads stay below
#pragma unroll
      for (int i = 0; i < 4; ++i) aq[i] = *(const bf16v8*)&Al[abase + (4 + i) * 512];
      P1;
#pragma unroll
      for (int i = 0; i < 4; ++i) {
        acc[4 + i][0] = __builtin_amdgcn_mfma_f32_16x16x32_bf16(aq[i], bq0, acc[4 + i][0], 0, 0, 0);
        acc[4 + i][1] = __builtin_amdgcn_mfma_f32_16x16x32_bf16(aq[i], bq1, acc[4 + i][1], 0, 0, 0);
      }
      P0;
      if (kt + 1 < NT) { VMC0; }
      BARF;
    }
  }

  // Epilogue. C/D layout: col = lane&15, row = (lane>>4)*4 + reg  [HW-verified]
  const int r0 = (lane >> 4) * 4;
  const int c0 = lane & 15;
  const int mrowB = m0 + wm * 128 + r0;       // + i*16 + r
  const int ncolB = n0 + wn * 32 + c0;        // + j*16

  if (MODE == 0) {
    if (n0 < 1536) {  // Q or K region (block-uniform: 128 | 768)
      unsigned short* dst = (n0 < 768) ? Cq : Ck;
      const int cb = (n0 < 768) ? 0 : 768;
#pragma unroll
      for (int i = 0; i < 8; ++i)
#pragma unroll
        for (int j = 0; j < 2; ++j)
#pragma unroll
          for (int r = 0; r < 4; ++r)
            dst[(size_t)(mrowB + i * 16 + r) * DD + (ncolB + j * 16 - cb)] = f2b(acc[i][j][r]);
    } else {  // V region: store transposed Vt[b][e][n]
#pragma unroll
      for (int i = 0; i < 8; ++i) {
        int row = mrowB + i * 16;          // global token index = b*2048 + n
        int bb = row >> 11, nn = row & 2047;
#pragma unroll
        for (int j = 0; j < 2; ++j) {
          int e = ncolB + j * 16 - 1536;
          ushort4v pk;
#pragma unroll
          for (int r = 0; r < 4; ++r) pk[r] = f2b(acc[i][j][r]);
          *(ushort4v*)&Cv[((size_t)(bb * DD + e)) * NN + nn] = pk;
        }
      }
    }
  } else if (MODE == 1) {
    unsigned short* dst = Cq + (size_t)bz * cStride;
#pragma unroll
    for (int i = 0; i < 8; ++i)
#pragma unroll
      for (int j = 0; j < 2; ++j)
#pragma unroll
        for (int r = 0; r < 4; ++r)
          dst[(size_t)(mrowB + i * 16 + r) * NN + (ncolB + j * 16)] = f2b(acc[i][j][r]);
  } else {
    float* dst = Cf + (size_t)bz * cStride;
#pragma unroll
    for (int i = 0; i < 8; ++i)
#pragma unroll
      for (int j = 0; j < 2; ++j)
#pragma unroll
        for (int r = 0; r < 4; ++r)
          dst[(size_t)(mrowB + i * 16 + r) * DD + (ncolB + j * 16)] = acc[i][j][r];
  }
}

// ---------------- masked softmax, in-place on bf16 S rows ----------------
__global__ __launch_bounds__(256) void softmax_mask(unsigned short* __restrict__ S,
                                                    const int* __restrict__ mask) {
  int row = blockIdx.x;            // 0..16383
  int bb = row >> 11;
  unsigned short* sr = S + (size_t)row * NN;
  const int* mr = mask + bb * NN;
  int t = threadIdx.x;

  ushort8v pk = *(const ushort8v*)&sr[t * 8];
  float v[8];
  int msk[8];
#pragma unroll
  for (int j = 0; j < 8; ++j) msk[j] = mr[t * 8 + j];
  float mx = -1e30f;
#pragma unroll
  for (int j = 0; j < 8; ++j) {
    v[j] = b2f(pk[j]);
    if (!msk[j]) mx = fmaxf(mx, v[j]);
  }
  for (int o = 32; o > 0; o >>= 1) mx = fmaxf(mx, __shfl_xor(mx, o));
  __shared__ float redm[4], reds[4];
  int w = t >> 6, lane = t & 63;
  if (lane == 0) redm[w] = mx;
  __syncthreads();
  mx = fmaxf(fmaxf(redm[0], redm[1]), fmaxf(redm[2], redm[3]));

  float e[8];
  float sum = 0.f;
#pragma unroll
  for (int j = 0; j < 8; ++j) {
    e[j] = msk[j] ? 0.f : __expf(v[j] - mx);
    sum += e[j];
  }
  for (int o = 32; o > 0; o >>= 1) sum += __shfl_xor(sum, o);
  if (lane == 0) reds[w] = sum;
  __syncthreads();
  sum = reds[0] + reds[1] + reds[2] + reds[3];
  float inv = 1.0f / sum;

  ushort8v op;
#pragma unroll
  for (int j = 0; j < 8; ++j) op[j] = f2b(e[j] * inv);
  *(ushort8v*)&sr[t * 8] = op;
}

extern "C" void kernel_launch(void* const* d_in, const int* in_sizes, int n_in,
                              void* d_out, int out_size, void* d_ws, size_t ws_size,
                              hipStream_t stream) {
  const float* features = (const float*)d_in[0];
  const int* mask       = (const int*)d_in[1];
  const float* Wq       = (const float*)d_in[2];
  const float* Wk       = (const float*)d_in[3];
  const float* Wv       = (const float*)d_in[4];
  const float* gamma    = (const float*)d_in[5];
  const float* beta     = (const float*)d_in[6];
  float* out = (float*)d_out;

  char* ws = (char*)d_ws;
  size_t off = 0;
  auto alloc = [&](size_t bytes) {
    char* p = ws + off;
    off += (bytes + 255) & ~(size_t)255;
    return p;
  };
  unsigned short* Wcat = (unsigned short*)alloc((size_t)(2304 + 64) * DD * 2);
  unsigned short* Qb   = (unsigned short*)alloc((size_t)BB * NN * DD * 2);
  unsigned short* Kb   = (unsigned short*)alloc((size_t)BB * NN * DD * 2);
  unsigned short* Vt   = (unsigned short*)alloc(((size_t)BB * DD + 64) * NN * 2);
  // S (67 MB) aliases the X buffer region: X is dead once GEMM0 completes.
  char* last = alloc((size_t)BB * NN * NN * 2);
  unsigned short* Sb = (unsigned short*)last;
  unsigned short* Xb = (unsigned short*)last;  // first 25 MB of the S region

  ln_kernel<<<BB * NN, 256, 0, stream>>>(features, gamma, beta, Xb);
  wconvert<<<(3 * DD * DD + 255) / 256, 256, 0, stream>>>(Wq, Wk, Wv, Wcat);

  // QKV projection: [16384,768] x [2304,768]^T ; 18 x 64 = 1152 blocks, 2/CU resident
  gemm128<0><<<dim3(2304 / 128, (BB * NN) / 256, 1), 512, 0, stream>>>(
      Xb, Wcat, Qb, Kb, Vt, nullptr, DD, DD, DD, 0, 0, 0);

  // Scores: per batch [2048,768] x [2048,768]^T -> S bf16 ; 16x8x8 = 1024 blocks
  gemm128<1><<<dim3(NN / 128, NN / 256, BB), 512, 0, stream>>>(
      Qb, Kb, Sb, nullptr, nullptr, nullptr, DD, DD, DD,
      (long)NN * DD, (long)NN * DD, (long)NN * NN);

  softmax_mask<<<BB * NN, 256, 0, stream>>>(Sb, mask);

  // Context: per batch P[2048,2048] x Vt[768,2048]^T -> f32 out ; 6x8x8 = 384 blocks
  gemm128<2><<<dim3(DD / 128, NN / 256, BB), 512, 0, stream>>>(
      Sb, Vt, nullptr, nullptr, nullptr, out, NN, NN, NN,
      (long)NN * NN, (long)DD * NN, (long)NN * DD);
}